// Round 9
// baseline (52.451 us; speedup 1.0000x reference)
//
#include <hip/hip_runtime.h>
#include <hip/hip_bf16.h>

// MaskedDenseLayerMultiMasks: out[b,m,o] = sum_i x[b,m,i] * kernel[i,o] * masks[m,i,o]
// Round 9: r8 + counted-vmcnt pipeline (T4 done right):
//   - Mf ring[3]: mask tile DMA'd 2 iters ahead via global_load_lds
//   - end-of-iter wait = s_waitcnt vmcnt(2)  (NEVER 0 in the main loop):
//     tile t+1's DMAs (issued iter t-1, FIFO-older) are guaranteed landed,
//     tile t+2's stay in flight
//   - single-buffered As/Bs (barriers already separate read(t) / write(t+1))
//     -> 66.5 KB LDS, still 2 blocks/CU
//   - X/Kn issued before DMA (sched_barrier-fenced) so their dataflow waits
//     never drain the DMA queue
//   - T5 setprio around MFMA cluster

#define BATCH 512
#define NMASK 16
#define IN_D  1024
#define OUT_D 1024

#define BM 128
#define BN 128
#define BK 32
#define NT (IN_D / BK)   // 32
#define AKP 40           // A LDS k-stride (80B rows)
#define BKP 34           // B LDS k-stride (68B rows)
#define MFSZ (BK * BN)   // 4096 floats per mask tile
#define THREADS 512

using bf16x8 = __attribute__((ext_vector_type(8))) __bf16;
using bf16x4 = __attribute__((ext_vector_type(4))) __bf16;
using f32x4  = __attribute__((ext_vector_type(4))) float;
using f32x2  = __attribute__((ext_vector_type(2))) float;

typedef const __attribute__((address_space(1))) void gvoid_t;
typedef __attribute__((address_space(3))) void lvoid_t;

__device__ __forceinline__ void dma16(const void* g, const void* l) {
    __builtin_amdgcn_global_load_lds((gvoid_t*)(uintptr_t)g,
                                     (lvoid_t*)(uintptr_t)l, 16, 0, 0);
}

__global__ void __launch_bounds__(THREADS, 4)
mdl_mfma_kernel(const float* __restrict__ X,   // (B, M, I)
                const float* __restrict__ Kn,  // (I, O)
                const float* __restrict__ Mk,  // (M, I, O)
                float* __restrict__ Out)       // (B, M, O)
{
    __shared__ __align__(16) float          Mf[3 * MFSZ];    // 48 KiB (ring)
    __shared__ __align__(16) unsigned short As[BM * AKP];    // 10 KiB
    __shared__ __align__(16) unsigned short Bs[BN * BKP];    // 8.5 KiB

    const int t = threadIdx.x;
    const int l = t & 63;
    const int w = t >> 6;          // wave 0..7

    // XCD-aware bijective swizzle: 512 wgs, 8 XCDs, 64 contiguous wgs/XCD.
    const int raw = blockIdx.x;
    const int wg  = (raw & 7) * 64 + (raw >> 3);
    const int m   = wg >> 5;          // 0..15
    const int ob  = (wg >> 2) & 7;    // 0..7
    const int bb  = wg & 3;           // 0..3

    // wave -> 64x32 sub-tile (r4's proven map)
    const int wr = w >> 2;            // 0..1
    const int wc = w & 3;             // 0..3

    f32x4 acc[4][2];
#pragma unroll
    for (int mi = 0; mi < 4; ++mi)
#pragma unroll
        for (int ni = 0; ni < 2; ++ni)
            acc[mi][ni] = (f32x4){0.f, 0.f, 0.f, 0.f};

    // A staging: row = t>>2 (0..127), k-half = (t&3)*8
    const int a_row = t >> 2;
    const int a_kh  = (t & 3) * 8;
    // B staging: thread owns [4k][2o]: o2 = 2*(t&63), k4 = w*4
    const int o2 = (t & 63) * 2;
    const int k4 = w * 4;

    const int obase = ob * BN;
    const float* Xa  = X + ((size_t)(bb * BM + a_row) * NMASK + m) * IN_D + a_kh;
    const float* Knb = Kn + obase + o2;
    const float* Mkm = Mk + (size_t)m * IN_D * OUT_D;

    // DMA map (r8-proven): lane l covers mask row k = j*16 + w*2 + (l>>5),
    // o-quad (l&31)*4; LDS base (wave-uniform) = c*MFSZ + j*2048 + w*256.
    auto DMA = [&](int tile, int c) {
        const int kt = tile * BK;
#pragma unroll
        for (int j = 0; j < 2; ++j) {
            const int k = j * 16 + w * 2 + (l >> 5);
            const float* gsrc = Mkm + (size_t)(kt + k) * OUT_D + obase + (l & 31) * 4;
            const float* ldst = &Mf[c * MFSZ + j * 2048 + w * 256];
            dma16(gsrc, ldst);
        }
    };

    auto MFMA_PHASE = [&]() {
        const int kg = (l >> 4) * 8;
        bf16x8 bfv[2];
#pragma unroll
        for (int ni = 0; ni < 2; ++ni) {
            const int n = wc * 32 + ni * 16 + (l & 15);
            bf16x4 lo = *(const bf16x4*)(&Bs[n * BKP + kg]);
            bf16x4 hi = *(const bf16x4*)(&Bs[n * BKP + kg + 4]);
            bf16x8 f;
            f[0] = lo[0]; f[1] = lo[1]; f[2] = lo[2]; f[3] = lo[3];
            f[4] = hi[0]; f[5] = hi[1]; f[6] = hi[2]; f[7] = hi[3];
            bfv[ni] = f;
        }
#pragma unroll
        for (int mi = 0; mi < 4; ++mi) {
            const int r = wr * 64 + mi * 16 + (l & 15);
            bf16x8 af = *(const bf16x8*)(&As[r * AKP + kg]);
#pragma unroll
            for (int ni = 0; ni < 2; ++ni)
                acc[mi][ni] = __builtin_amdgcn_mfma_f32_16x16x32_bf16(
                    af, bfv[ni], acc[mi][ni], 0, 0, 0);
        }
    };

    // ---- prologue: DMA tiles 0,1 into bufs 0,1; need tile 0 -> vmcnt(2) ----
    DMA(0, 0);
    DMA(1, 1);
    asm volatile("s_waitcnt vmcnt(2)" ::: "memory");
    __builtin_amdgcn_sched_barrier(0);
    __builtin_amdgcn_s_barrier();
    __builtin_amdgcn_sched_barrier(0);

    int c_cur = 0, c_nxt = 1, c_far = 2;

    for (int tt = 0; tt < NT; ++tt) {
        const int kt = tt * BK;

        // (1) X/Kn loads for THIS tile -- issued FIRST so their dataflow waits
        //     never drain the DMA queue (FIFO).
        f32x4 xv0 = *(const f32x4*)(Xa + kt);
        f32x4 xv1 = *(const f32x4*)(Xa + kt + 4);
        f32x2 kv[4];
#pragma unroll
        for (int r = 0; r < 4; ++r)
            kv[r] = *(const f32x2*)(Knb + (size_t)(kt + k4 + r) * OUT_D);
        __builtin_amdgcn_sched_barrier(0);

        // (2) DMA tile tt+2 into c_far (dummy re-DMA of tile 0 near the tail:
        //     keeps the FIFO depth uniform so vmcnt(2) stays correct).
        const int tile_pf = (tt + 2 < NT) ? (tt + 2) : 0;
        DMA(tile_pf, c_far);
        __builtin_amdgcn_sched_barrier(0);

        // (3) staging: Mf[c_cur] (landed: guaranteed by last iter's vmcnt(2))
        {
            f32x2 mvv[4];
#pragma unroll
            for (int r = 0; r < 4; ++r)
                mvv[r] = *(const f32x2*)(&Mf[c_cur * MFSZ + (k4 + r) * BN + o2]);
#pragma unroll
            for (int c = 0; c < 2; ++c) {
                bf16x4 v;
#pragma unroll
                for (int r = 0; r < 4; ++r)
                    v[r] = (__bf16)(kv[r][c] * mvv[r][c]);
                *(bf16x4*)(&Bs[(o2 + c) * BKP + k4]) = v;
            }
            bf16x8 va;
#pragma unroll
            for (int j = 0; j < 4; ++j) {
                va[j]     = (__bf16)xv0[j];
                va[4 + j] = (__bf16)xv1[j];
            }
            *(bf16x8*)(&As[a_row * AKP + a_kh]) = va;
        }

        // (4) staging visible to all waves (LDS only -- no vmcnt here)
        asm volatile("s_waitcnt lgkmcnt(0)" ::: "memory");
        __builtin_amdgcn_sched_barrier(0);
        __builtin_amdgcn_s_barrier();
        __builtin_amdgcn_sched_barrier(0);

        // (5) compute (frag reads consumed by MFMA => lgkm drained in-wave
        //     before the end barrier; safe vs next iter's staging writes)
        __builtin_amdgcn_s_setprio(1);
        MFMA_PHASE();
        __builtin_amdgcn_s_setprio(0);

        // (6) COUNTED wait: leave tile tt+2's 2 DMAs in flight; tile tt+1's
        //     (FIFO-older) are guaranteed complete. Never vmcnt(0) here.
        asm volatile("s_waitcnt vmcnt(2)" ::: "memory");
        __builtin_amdgcn_sched_barrier(0);
        __builtin_amdgcn_s_barrier();
        __builtin_amdgcn_sched_barrier(0);

        // rotate ring
        const int tmp = c_cur; c_cur = c_nxt; c_nxt = c_far; c_far = tmp;
    }

    asm volatile("s_waitcnt vmcnt(0)" ::: "memory");  // drain dummy DMAs

    // ---- epilogue: C/D layout col = l&15, row = (l>>4)*4 + reg ----
    const int r0 = bb * BM + wr * 64 + (l >> 4) * 4;
    const int c0 = ob * BN + wc * 32 + (l & 15);
#pragma unroll
    for (int mi = 0; mi < 4; ++mi) {
#pragma unroll
        for (int j = 0; j < 4; ++j) {
            const size_t row = (size_t)(r0 + mi * 16 + j);
            float* op = Out + (row * NMASK + m) * OUT_D + c0;
#pragma unroll
            for (int ni = 0; ni < 2; ++ni)
                op[ni * 16] = acc[mi][ni][j];
        }
    }
}

extern "C" void kernel_launch(void* const* d_in, const int* in_sizes, int n_in,
                              void* d_out, int out_size, void* d_ws, size_t ws_size,
                              hipStream_t stream) {
    (void)in_sizes; (void)n_in; (void)d_ws; (void)ws_size; (void)out_size;
    const float* X  = (const float*)d_in[0];
    const float* Kn = (const float*)d_in[1];
    const float* Mk = (const float*)d_in[2];
    float* Out = (float*)d_out;

    const int nblocks = (BATCH / BM) * (OUT_D / BN) * NMASK;  // 512
    mdl_mfma_kernel<<<nblocks, THREADS, 0, stream>>>(X, Kn, Mk, Out);
}